// Round 2
// baseline (210.902 us; speedup 1.0000x reference)
//
#include <hip/hip_runtime.h>

// FFM pairwise interaction: out[b] = sum_{i<j} sum_k in[b,i,j,k] * in[b,j,i,k]
// B=8192, F=39, K=16, fp32. Memory-bound; floor = 777MB read once.
//
// Strategy: both global streams fully coalesced.
//   Phase A: stream upper-triangle 64B blocks (row-major, contiguous per row)
//            into an LDS stash (741 * 64B = 47.4 KB).
//   Phase B: stream lower-triangle 64B blocks (row-major, contiguous per row),
//            dot each against its stashed transpose partner from LDS.

#define FF    39
#define KK    16
#define NBLK  (FF * (FF - 1) / 2)   // 741 blocks per triangle
#define ITEMS (NBLK * 4)            // 2964 float4 items per phase
#define SLICE (FF * FF * KK)        // 24336 floats per batch
#define NTHR  256

__global__ __launch_bounds__(NTHR) void ffm_kernel(const float* __restrict__ in,
                                                   float* __restrict__ out,
                                                   int nbatch) {
    __shared__ float stash[NBLK * KK];   // 47424 B
    __shared__ float red[NTHR / 64];

    const int tid = threadIdx.x;
    const int b = blockIdx.x;
    if (b >= nbatch) return;
    const float* base = in + (size_t)b * SLICE;

    // ---- Phase A: upper triangle -> LDS (coalesced global reads) ----
    // Upper-tri blocks enumerated row-major: row i holds blocks (i, i+1..38).
    // cumA(i) = i*(77-i)/2 blocks before row i.
    for (int m = tid; m < ITEMS; m += NTHR) {
        const int mb = m >> 2;        // triangle block index 0..740
        const int q  = m & 3;         // float4 within block
        int i = (int)((77.0f - sqrtf((float)(5929 - 8 * mb))) * 0.5f);
        while (i * (77 - i) / 2 > mb) --i;                 // fixup (0-1 iters)
        while ((i + 1) * (76 - i) / 2 <= mb) ++i;
        const int j = i + 1 + (mb - i * (77 - i) / 2);
        const float4 x = *reinterpret_cast<const float4*>(base + (i * FF + j) * KK + q * 4);
        *reinterpret_cast<float4*>(&stash[mb * KK + q * 4]) = x;
    }
    __syncthreads();

    // ---- Phase B: lower triangle (coalesced) x LDS partner ----
    // Lower-tri blocks row-major: row j holds blocks (j, 0..j-1).
    // cumB(j) = j*(j-1)/2 blocks before row j.
    float acc = 0.f;
    for (int m = tid; m < ITEMS; m += NTHR) {
        const int mb = m >> 2;
        const int q  = m & 3;
        int j = (int)((1.0f + sqrtf((float)(1 + 8 * mb))) * 0.5f);
        while (j * (j - 1) / 2 > mb) --j;                  // fixup (0-1 iters)
        while (j * (j + 1) / 2 <= mb) ++j;
        const int i = mb - j * (j - 1) / 2;                // 0 <= i < j
        const float4 x = *reinterpret_cast<const float4*>(base + (j * FF + i) * KK + q * 4);
        const int tU = i * (77 - i) / 2 + (j - i - 1);     // partner (i,j) slot
        const float4 y = *reinterpret_cast<const float4*>(&stash[tU * KK + q * 4]);
        acc += x.x * y.x + x.y * y.y + x.z * y.z + x.w * y.w;
    }

    // ---- Reduce 256 threads -> scalar ----
    #pragma unroll
    for (int off = 32; off > 0; off >>= 1)
        acc += __shfl_down(acc, off, 64);
    const int wave = tid >> 6;
    if ((tid & 63) == 0) red[wave] = acc;
    __syncthreads();
    if (tid == 0) {
        float s = 0.f;
        #pragma unroll
        for (int w = 0; w < NTHR / 64; ++w) s += red[w];
        out[b] = s;
    }
}

extern "C" void kernel_launch(void* const* d_in, const int* in_sizes, int n_in,
                              void* d_out, int out_size, void* d_ws, size_t ws_size,
                              hipStream_t stream) {
    const float* in = (const float*)d_in[0];
    float* out = (float*)d_out;
    const int nbatch = out_size;  // 8192

    ffm_kernel<<<dim3(nbatch), dim3(NTHR), 0, stream>>>(in, out, nbatch);
}

// Round 3
// 134.576 us; speedup vs baseline: 1.5672x; 1.5672x over previous
//
#include <hip/hip_runtime.h>

// FFM pairwise interaction: out[b] = sum_{i<j} sum_k in[b,i,j,k] * in[b,j,i,k]
// B=8192, F=39, K=16, fp32. Memory-bound; fetch floor ~797 MB -> ~126 us.
//
// R1 structure (max occupancy, both streams full-line at L1 granularity),
// minus per-item overhead: byte-offset tables -> saddr+voffset addressing,
// q*16 folds into the load's immediate offset; unroll 2 for load pipelining.

#define FF    39
#define KK    16
#define NPAIR (FF * (FF - 1) / 2)   // 741
#define ITEMS (NPAIR * 4)           // 2964 float4 items per batch
#define SLICE (FF * FF * KK)        // 24336 floats per batch
#define NTHR  256

__global__ __launch_bounds__(NTHR) void ffm_kernel(const float* __restrict__ in,
                                                   float* __restrict__ out,
                                                   int nbatch) {
    __shared__ int xoffB[NPAIR];   // byte offset of block [i,j,0]
    __shared__ int yoffB[NPAIR];   // byte offset of block [j,i,0]
    __shared__ float red[NTHR / 64];

    const int tid = threadIdx.x;

    // Pair -> byte-offset table (once per block). Row decode via closed form.
    for (int p = tid; p < NPAIR; p += NTHR) {
        int i = (int)((77.0f - sqrtf((float)(5929 - 8 * p))) * 0.5f);
        while (i * (77 - i) / 2 > p) --i;                  // fixup (rare)
        while ((i + 1) * (76 - i) / 2 <= p) ++i;
        const int j = i + 1 + (p - i * (77 - i) / 2);
        xoffB[p] = (i * FF + j) * (KK * 4);
        yoffB[p] = (j * FF + i) * (KK * 4);
    }
    __syncthreads();

    const int b = blockIdx.x;
    if (b >= nbatch) return;
    const char* base = (const char*)(in + (size_t)b * SLICE);

    float acc = 0.f;
    #pragma unroll 2
    for (int m = tid; m < ITEMS; m += NTHR) {
        const int p  = m >> 2;
        const int qb = (m & 3) * 16;
        const int xo = xoffB[p] + qb;
        const int yo = yoffB[p] + qb;
        const float4 x = *reinterpret_cast<const float4*>(base + xo);
        const float4 y = *reinterpret_cast<const float4*>(base + yo);
        acc += x.x * y.x + x.y * y.y + x.z * y.z + x.w * y.w;
    }

    // 256 -> 1 reduce: wave shuffle, then cross-wave via LDS.
    #pragma unroll
    for (int off = 32; off > 0; off >>= 1)
        acc += __shfl_down(acc, off, 64);
    const int wave = tid >> 6;
    if ((tid & 63) == 0) red[wave] = acc;
    __syncthreads();
    if (tid == 0) {
        float s = 0.f;
        #pragma unroll
        for (int w = 0; w < NTHR / 64; ++w) s += red[w];
        out[b] = s;
    }
}

extern "C" void kernel_launch(void* const* d_in, const int* in_sizes, int n_in,
                              void* d_out, int out_size, void* d_ws, size_t ws_size,
                              hipStream_t stream) {
    const float* in = (const float*)d_in[0];
    float* out = (float*)d_out;
    const int nbatch = out_size;  // 8192

    ffm_kernel<<<dim3(nbatch), dim3(NTHR), 0, stream>>>(in, out, nbatch);
}